// Round 5
// baseline (3412.431 us; speedup 1.0000x reference)
//
#include <hip/hip_runtime.h>

#define SEQ_L 1000
#define HID   51
#define NB    2      // batch elements per block; grid = 1024/2 = 512 = 2 blocks/CU

__device__ __forceinline__ float sigmoid_f(float x) {
    return 1.0f / (1.0f + __expf(-x));
}

// Two-cell pipelined LSTM, 1-step skew, 2 blocks/CU for latency hiding.
// Thread (wave k, lane l<51) owns cell-1 gate row k*51+l AND cell-2 gate row
// k*51+l (all weights in VGPRs; fully unrolled -> static indices -> no scratch).
// Phase X: gates1(i) || gates2(i-1)  -- share the h1s[j] broadcast read.
// Phase Y: update1(i) (waves 0..NB-1 as batch cols) || update2(i-1) + out proj.
__global__ __launch_bounds__(256, 2)
void lstm2_kernel(const float* __restrict__ input,
                  const float* __restrict__ W1, const float* __restrict__ b1,
                  const float* __restrict__ R1, const float* __restrict__ W2,
                  const float* __restrict__ b2, const float* __restrict__ R2,
                  const float* __restrict__ w_out, const float* __restrict__ b_out,
                  float* __restrict__ out)
{
    const int tid = threadIdx.x;
    const int n0  = blockIdx.x * NB;
    const int w   = tid >> 6;          // phase X: gate index k; phase Y: batch col
    const int l   = tid & 63;          // hidden unit
    const bool act = (l < HID);

    __shared__ float2 h1s[HID];        // h1 state, [hid] x NB batches
    __shared__ float2 h2s[HID];        // h2 state
    __shared__ float  g1a[NB][4 * HID];
    __shared__ float  g2a[NB][4 * HID];
    __shared__ float  xs[NB][SEQ_L + 1];   // +1 zero pad: epilogue reads xs[b][L]

    // stage input rows (coalesced along L) + zero the pad column
    for (int idx = tid; idx < NB * (SEQ_L + 1); idx += 256) {
        int b = idx / (SEQ_L + 1);
        int t = idx - b * (SEQ_L + 1);
        xs[b][t] = (t < SEQ_L) ? input[(n0 + b) * SEQ_L + t] : 0.f;
    }
    if (tid < HID) {
        h1s[tid] = float2{0.f, 0.f};
        h2s[tid] = float2{0.f, 0.f};
    }

    // ---- weights in registers (fully unrolled loops -> VGPRs, never scratch)
    const int r = w * HID + l;         // gate row (valid when act)
    float wR1[HID], wW2[HID], wR2[HID];
    float w1r = 0.f, b1r = 0.f, b2r = 0.f;
    if (act) {
        w1r = W1[r]; b1r = b1[r]; b2r = b2[r];
        #pragma unroll
        for (int j = 0; j < HID; ++j) {
            wR1[j] = R1[r * HID + j];
            wW2[j] = W2[r * HID + j];
            wR2[j] = R2[r * HID + j];
        }
    }
    const bool is_cand = (w == 2);     // wave-uniform: wave 2's rows are the tanh gate
    const float sc = is_cand ? 2.f : 1.f;   // tanh(x) = 2*sigmoid(2x)-1

    float c1 = 0.f, c2 = 0.f;          // cell states for (batch w, hid l), w < NB
    const float woutr = act ? w_out[l] : 0.f;
    const float bout  = b_out[0];
    float* h1p = (float*)h1s;
    float* h2p = (float*)h2s;

    __syncthreads();

    for (int i = 0; i <= SEQ_L; ++i) {     // i: cell-1 time; i-1: cell-2 time
        const int t2 = i - 1;
        // ---------- phase X: gates, both cells, shared h1s reads ----------
        if (act) {
            float a0 = fmaf(w1r, xs[0][i], b1r);
            float a1 = fmaf(w1r, xs[1][i], b1r);
            float d0 = b2r, d1 = b2r;
            #pragma unroll
            for (int j = 0; j < HID; ++j) {
                float2 h = h1s[j];             // one broadcast b64 feeds 4 FMAs
                a0 = fmaf(wR1[j], h.x, a0);  d0 = fmaf(wW2[j], h.x, d0);
                a1 = fmaf(wR1[j], h.y, a1);  d1 = fmaf(wW2[j], h.y, d1);
            }
            #pragma unroll
            for (int j = 0; j < HID; ++j) {
                float2 h = h2s[j];
                d0 = fmaf(wR2[j], h.x, d0);
                d1 = fmaf(wR2[j], h.y, d1);
            }
            float s;
            s = sigmoid_f(sc * a0); g1a[0][r] = is_cand ? fmaf(2.f, s, -1.f) : s;
            s = sigmoid_f(sc * a1); g1a[1][r] = is_cand ? fmaf(2.f, s, -1.f) : s;
            s = sigmoid_f(sc * d0); g2a[0][r] = is_cand ? fmaf(2.f, s, -1.f) : s;
            s = sigmoid_f(sc * d1); g2a[1][r] = is_cand ? fmaf(2.f, s, -1.f) : s;
        }
        __syncthreads();   // gates ready; previous-phase h1s/h2s readers done
        // ---------- phase Y: updates (waves 0..NB-1 act as batch columns) ----------
        if (w < NB) {
            if (i < SEQ_L && act) {      // update1(i): h1s <- h1(i)
                float gi = g1a[w][l];
                float gf = g1a[w][HID + l];
                float gc = g1a[w][2 * HID + l];
                float go = g1a[w][3 * HID + l];
                c1 = fmaf(gf, c1, gi * gc);
                h1p[l * NB + w] = go * fmaf(2.f, sigmoid_f(2.f * c1), -1.f);
            }
            if (t2 >= 0) {               // update2(i-1) + out(i-1)
                float part = 0.f;
                if (act) {
                    float gi = g2a[w][l];
                    float gf = g2a[w][HID + l];
                    float gc = g2a[w][2 * HID + l];
                    float go = g2a[w][3 * HID + l];
                    c2 = fmaf(gf, c2, gi * gc);
                    float h2v = go * fmaf(2.f, sigmoid_f(2.f * c2), -1.f);
                    h2p[l * NB + w] = h2v;
                    part = woutr * h2v;
                }
                #pragma unroll
                for (int off = 32; off > 0; off >>= 1)
                    part += __shfl_down(part, off, 64);
                if (l == 0) out[(n0 + w) * SEQ_L + t2] = part + bout;
            }
        }
        __syncthreads();   // h1s/h2s published before next X reads them
    }
}

extern "C" void kernel_launch(void* const* d_in, const int* in_sizes, int n_in,
                              void* d_out, int out_size, void* d_ws, size_t ws_size,
                              hipStream_t stream)
{
    const float* input = (const float*)d_in[0];
    const float* W1    = (const float*)d_in[1];
    const float* b1    = (const float*)d_in[2];
    const float* R1    = (const float*)d_in[3];
    const float* W2    = (const float*)d_in[4];
    const float* b2    = (const float*)d_in[5];
    const float* R2    = (const float*)d_in[6];
    const float* w_out = (const float*)d_in[7];
    const float* b_out = (const float*)d_in[8];
    float* out = (float*)d_out;

    dim3 grid(1024 / NB);
    dim3 block(256);
    hipLaunchKernelGGL(lstm2_kernel, grid, block, 0, stream,
                       input, W1, b1, R1, W2, b2, R2, w_out, b_out, out);
}